// Round 5
// baseline (305.889 us; speedup 1.0000x reference)
//
#include <hip/hip_runtime.h>
#include <math.h>

// Problem constants (fixed by setup_inputs)
constexpr int B  = 8;
constexpr int CF = 256;
constexpr int HF = 128;
constexpr int WF = 128;
constexpr int HP = 512;
constexpr int WP = 512;
constexpr long long NTOT = (long long)B * CF * HF * WF;   // 33,554,432

typedef float f4 __attribute__((ext_vector_type(4)));

// ws layout (bytes):
//   [256, 256+512K)     : pooled mask (8*128*128 f32)  ("mds")
//   [IMG_OFF, +1.5M)    : img_ds (8*3*128*128 f32)
//   [PART_OFF, +32K)    : per-block double2 partials
constexpr size_t DH_OFF    = 256;
constexpr size_t IMG_OFF   = DH_OFF + (size_t)B * HF * WF * sizeof(float);
constexpr size_t PART_OFF  = IMG_OFF + (size_t)B * 3 * HF * WF * sizeof(float);

constexpr int RBLOCKS  = 2048;
constexpr int RTHREADS = 256;
constexpr int PBLOCKS  = 512;   // pool blocks fused in front of the reduce grid
constexpr int RCHUNK   = 16384; // floats per reduce block (contiguous 64 KB)
// 2048 * 16384 = 33,554,432 = NTOT exactly.

// Fused pass 1:
//   blocks [0, PBLOCKS)            : 4x4 avg-pool img (3ch) + 4x4 max-pool mask ch0
//   blocks [PBLOCKS, PBLOCKS+2048) : per-block partial sum/sumsq over F
// NOTE (round-4 post-mortem): this kernel's ~77 us is dominated by the 512 MiB
// poison-fill's dirty-L3 write-back draining during our F-read -- access-pattern
// changes were ~neutral. Kept contiguous-per-block anyway.
__global__ void __launch_bounds__(RTHREADS) k_reduce_pool(
        const float* __restrict__ F,
        const float* __restrict__ img, const float* __restrict__ mask,
        float* __restrict__ img_ds, float* __restrict__ mds,
        double2* __restrict__ part) {
    __shared__ double ls[4], lq[4];
    const int bid = blockIdx.x;
    if (bid < PBLOCKS) {
        // ---- pool path (block-uniform branch) ----
        int t = bid * RTHREADS + threadIdx.x;        // [0, 131072) exactly
        int w = t & (WF - 1);
        int h = (t >> 7) & (HF - 1);
        int b = t >> 14;
        for (int c = 0; c < 3; ++c) {
            const float* p = img + (((b * 3 + c) * HP + h * 4) * WP + w * 4);
            float s = 0.0f;
            for (int r = 0; r < 4; ++r) {
                f4 v = *(const f4*)(p + r * WP);
                s += v.x + v.y + v.z + v.w;
            }
            img_ds[((b * 3 + c) << 14) | (h << 7) | w] = s * 0.0625f;
        }
        const float* pm = mask + (((b * 3) * HP + h * 4) * WP + w * 4);
        float m = 0.0f;
        for (int r = 0; r < 4; ++r) {
            f4 v = *(const f4*)(pm + r * WP);
            m = fmaxf(m, fmaxf(fmaxf(v.x, v.y), fmaxf(v.z, v.w)));
        }
        mds[t] = m;
        return;
    }
    // ---- reduce path: contiguous 64 KB stream per block ----
    const int rb = bid - PBLOCKS;
    const float* p = F + (size_t)rb * RCHUNK + threadIdx.x * 4;
    f4 v[16];
#pragma unroll
    for (int k = 0; k < 16; ++k)
        v[k] = *(const f4*)(p + k * (RTHREADS * 4));   // sequential 4 KB steps
    double s0 = 0, s1 = 0, s2 = 0, s3 = 0;
    double q0 = 0, q1 = 0, q2 = 0, q3 = 0;
#pragma unroll
    for (int k = 0; k < 16; k += 4) {
        {
            f4 w = v[k + 0];
            s0 += (double)((w.x + w.y) + (w.z + w.w));
            q0 += (double)((w.x * w.x + w.y * w.y) + (w.z * w.z + w.w * w.w));
        }
        {
            f4 w = v[k + 1];
            s1 += (double)((w.x + w.y) + (w.z + w.w));
            q1 += (double)((w.x * w.x + w.y * w.y) + (w.z * w.z + w.w * w.w));
        }
        {
            f4 w = v[k + 2];
            s2 += (double)((w.x + w.y) + (w.z + w.w));
            q2 += (double)((w.x * w.x + w.y * w.y) + (w.z * w.z + w.w * w.w));
        }
        {
            f4 w = v[k + 3];
            s3 += (double)((w.x + w.y) + (w.z + w.w));
            q3 += (double)((w.x * w.x + w.y * w.y) + (w.z * w.z + w.w * w.w));
        }
    }
    double s = (s0 + s1) + (s2 + s3);
    double q = (q0 + q1) + (q2 + q3);
    for (int off = 32; off > 0; off >>= 1) {
        s += __shfl_down(s, off);
        q += __shfl_down(q, off);
    }
    int lane = threadIdx.x & 63, wv = threadIdx.x >> 6;
    if (lane == 0) { ls[wv] = s; lq[wv] = q; }
    __syncthreads();
    if (threadIdx.x == 0) {
        double S_ = 0.0, Q_ = 0.0;
        for (int w = 0; w < 4; ++w) { S_ += ls[w]; Q_ += lq[w]; }
        part[rb] = make_double2(S_, Q_);
    }
}

// On-the-fly D: the reference's 5-iteration masked box-dilation on a 0/1 mask
// equals a capped Chebyshev distance transform: D = 2^-d where d (<=5) is the
// Chebyshev distance to the nearest nonzero pooled-mask pixel; 0 if d > 5;
// 1 if the pixel itself is nonzero. P(pixel==0) = 2^-16, so the search branch
// almost never executes.
__device__ __forceinline__ float dt_val(const float* __restrict__ mds,
                                        int ib, int h, int w) {
    int best = 6;
    for (int dh = -5; dh <= 5; ++dh) {
        int hh = h + dh;
        if ((unsigned)hh >= (unsigned)HF) continue;
        for (int dw = -5; dw <= 5; ++dw) {
            int ww = w + dw;
            if ((unsigned)ww >= (unsigned)WF) continue;
            if (mds[(ib << 14) | (hh << 7) | ww] != 0.0f) {
                int ad = abs(dh) > abs(dw) ? abs(dh) : abs(dw);
                best = best < ad ? best : ad;
            }
        }
    }
    const float tbl[7] = {1.0f, 0.5f, 0.25f, 0.125f, 0.0625f, 0.03125f, 0.0f};
    return tbl[best];
}

// Fused epilogue: per-block redundant stats reduction (2048 double2 = 32 KB,
// L2-broadcast) + on-the-fly D + channel-grouped normalization.
// k_dilate_stats is GONE (was ~8-12 us of serial 8-block latency + a launch).
// out stores are now PLAIN (allocating): if the poison fill's dirty out-lines
// are still in L3, overwriting them in-cache elides up to 134 MB of poison
// write-back (probe; NT was no-allocate).
constexpr int CGRP = 8;
__global__ void __launch_bounds__(256) k_final(const float* __restrict__ F,
                        const float* __restrict__ img_ds,
                        const float* __restrict__ mds,
                        const float* __restrict__ gw, const float* __restrict__ gb,
                        const float* __restrict__ bw, const float* __restrict__ bb,
                        const double2* __restrict__ part,
                        float* __restrict__ out) {
    // ---- stats preamble (identical result in every block) ----
    __shared__ double ls[4], lq[4];
    __shared__ float s_stats[2];
    {
        double s = 0.0, q = 0.0;
        for (int k = 0; k < 8; ++k) {
            double2 p = part[k * 256 + threadIdx.x];
            s += p.x; q += p.y;
        }
        for (int off = 32; off > 0; off >>= 1) {
            s += __shfl_down(s, off);
            q += __shfl_down(q, off);
        }
        int lane = threadIdx.x & 63, wv = threadIdx.x >> 6;
        if (lane == 0) { ls[wv] = s; lq[wv] = q; }
        __syncthreads();
        if (threadIdx.x == 0) {
            double S_ = (ls[0] + ls[1]) + (ls[2] + ls[3]);
            double Q_ = (lq[0] + lq[1]) + (lq[2] + lq[3]);
            double mean = S_ / (double)NTOT;
            double var  = (Q_ - (double)NTOT * mean * mean) / (double)(NTOT - 1);
            s_stats[0] = (float)mean;
            s_stats[1] = (float)(1.0 / sqrt(var * var + 1e-5));
        }
        __syncthreads();
    }
    const float meanf = s_stats[0];
    const float rstd  = s_stats[1];

    // grid = 1024 blocks x 256 threads.
    // blockIdx bits: [0:2) ihh4, [2:7) icg, [7:10) ib   (all block-uniform)
    // threadIdx bits: [0:5) iw, [5:8) ih_lo
    const int ihh4 = blockIdx.x & 3;
    const int icg  = (blockIdx.x >> 2) & 31;
    const int ib   = blockIdx.x >> 7;
    const int iw   = threadIdx.x & 31;
    const int w4   = iw * 4;
    const int c0   = icg * CGRP;

    const float* ip = img_ds + ((size_t)ib * 3 << 14);

    for (int sub = 0; sub < 4; ++sub) {
        const int ih = ihh4 * 32 + sub * 8 + (threadIdx.x >> 5);
        const int pixoff = (ih << 7) | w4;
        const int pix = (ib << 14) | pixoff;

        f4 m4 = *(const f4*)(mds + pix);
        f4 D;
        D.x = (m4.x != 0.0f) ? m4.x : dt_val(mds, ib, ih, w4 + 0);
        D.y = (m4.y != 0.0f) ? m4.y : dt_val(mds, ib, ih, w4 + 1);
        D.z = (m4.z != 0.0f) ? m4.z : dt_val(mds, ib, ih, w4 + 2);
        D.w = (m4.w != 0.0f) ? m4.w : dt_val(mds, ib, ih, w4 + 3);

        f4 R  = *(const f4*)(ip + ((0 << 14) | pixoff));
        f4 G  = *(const f4*)(ip + ((1 << 14) | pixoff));
        f4 Bl = *(const f4*)(ip + ((2 << 14) | pixoff));

        const size_t fbase = (((size_t)(ib * CF + c0)) << 14) + pixoff;

        f4 Fv[CGRP];
#pragma unroll
        for (int j = 0; j < CGRP; ++j)
            Fv[j] = *(const f4*)(F + fbase + ((size_t)j << 14));

#pragma unroll
        for (int j = 0; j < CGRP; ++j) {
            const int c = c0 + j;
            float g0 = gw[c * 3], g1 = gw[c * 3 + 1], g2 = gw[c * 3 + 2], gbi = gb[c];
            float b0 = bw[c * 3], b1 = bw[c * 3 + 1], b2 = bw[c * 3 + 2], bbi = bb[c];
            f4 o;
            {
                float gam = (R.x * g0 + G.x * g1 + Bl.x * g2 + gbi) * D.x;
                float bet = (R.x * b0 + G.x * b1 + Bl.x * b2 + bbi) * D.x;
                o.x = (Fv[j].x - meanf) * rstd * gam + bet;
            }
            {
                float gam = (R.y * g0 + G.y * g1 + Bl.y * g2 + gbi) * D.y;
                float bet = (R.y * b0 + G.y * b1 + Bl.y * b2 + bbi) * D.y;
                o.y = (Fv[j].y - meanf) * rstd * gam + bet;
            }
            {
                float gam = (R.z * g0 + G.z * g1 + Bl.z * g2 + gbi) * D.z;
                float bet = (R.z * b0 + G.z * b1 + Bl.z * b2 + bbi) * D.z;
                o.z = (Fv[j].z - meanf) * rstd * gam + bet;
            }
            {
                float gam = (R.w * g0 + G.w * g1 + Bl.w * g2 + gbi) * D.w;
                float bet = (R.w * b0 + G.w * b1 + Bl.w * b2 + bbi) * D.w;
                o.w = (Fv[j].w - meanf) * rstd * gam + bet;
            }
            *(f4*)(out + fbase + ((size_t)j << 14)) = o;   // plain (allocating) store
        }
    }
}

extern "C" void kernel_launch(void* const* d_in, const int* in_sizes, int n_in,
                              void* d_out, int out_size, void* d_ws, size_t ws_size,
                              hipStream_t stream) {
    const float* F_in  = (const float*)d_in[0];
    const float* img_p = (const float*)d_in[1];
    const float* mask  = (const float*)d_in[2];
    const float* gw    = (const float*)d_in[3];
    const float* gb    = (const float*)d_in[4];
    const float* bw    = (const float*)d_in[5];
    const float* bb    = (const float*)d_in[6];
    float* out = (float*)d_out;

    float*   mds    = (float*)((char*)d_ws + DH_OFF);
    float*   img_ds = (float*)((char*)d_ws + IMG_OFF);
    double2* part   = (double2*)((char*)d_ws + PART_OFF);

    k_reduce_pool<<<PBLOCKS + RBLOCKS, RTHREADS, 0, stream>>>(
        F_in, img_p, mask, img_ds, mds, part);
    k_final<<<8 * 32 * 4, 256, 0, stream>>>(
        F_in, img_ds, mds, gw, gb, bw, bb, part, out);
}

// Round 7
// 301.994 us; speedup vs baseline: 1.0129x; 1.0129x over previous
//
#include <hip/hip_runtime.h>
#include <math.h>

// Problem constants (fixed by setup_inputs)
constexpr int B  = 8;
constexpr int CF = 256;
constexpr int HF = 128;
constexpr int WF = 128;
constexpr int HP = 512;
constexpr int WP = 512;
constexpr long long NTOT = (long long)B * CF * HF * WF;   // 33,554,432

typedef float f4 __attribute__((ext_vector_type(4)));

// ws layout (bytes):
//   [256, 256+512K)     : pooled mask (8*128*128 f32)  ("mds")
//   [IMG_OFF, +1.5M)    : img_ds (8*3*128*128 f32)
//   [PART_OFF, +32K)    : per-block double2 partials
constexpr size_t DH_OFF    = 256;
constexpr size_t IMG_OFF   = DH_OFF + (size_t)B * HF * WF * sizeof(float);
constexpr size_t PART_OFF  = IMG_OFF + (size_t)B * 3 * HF * WF * sizeof(float);

constexpr int RBLOCKS  = 2048;
constexpr int RTHREADS = 256;
constexpr int PBLOCKS  = 512;   // pool blocks fused in front of the reduce grid
constexpr int RCHUNK   = 16384; // floats per reduce block (contiguous 64 KB)
// 2048 * 16384 = 33,554,432 = NTOT exactly.

// Fused pass 1:
//   blocks [0, PBLOCKS)            : 4x4 avg-pool img (3ch) + 4x4 max-pool mask ch0
//   blocks [PBLOCKS, PBLOCKS+2048) : per-block partial sum/sumsq over F
__global__ void __launch_bounds__(RTHREADS) k_reduce_pool(
        const float* __restrict__ F,
        const float* __restrict__ img, const float* __restrict__ mask,
        float* __restrict__ img_ds, float* __restrict__ mds,
        double2* __restrict__ part) {
    __shared__ double ls[4], lq[4];
    const int bid = blockIdx.x;
    if (bid < PBLOCKS) {
        // ---- pool path (block-uniform branch) ----
        int t = bid * RTHREADS + threadIdx.x;        // [0, 131072) exactly
        int w = t & (WF - 1);
        int h = (t >> 7) & (HF - 1);
        int b = t >> 14;
        for (int c = 0; c < 3; ++c) {
            const float* p = img + (((b * 3 + c) * HP + h * 4) * WP + w * 4);
            float s = 0.0f;
            for (int r = 0; r < 4; ++r) {
                f4 v = *(const f4*)(p + r * WP);
                s += v.x + v.y + v.z + v.w;
            }
            img_ds[((b * 3 + c) << 14) | (h << 7) | w] = s * 0.0625f;
        }
        const float* pm = mask + (((b * 3) * HP + h * 4) * WP + w * 4);
        float m = 0.0f;
        for (int r = 0; r < 4; ++r) {
            f4 v = *(const f4*)(pm + r * WP);
            m = fmaxf(m, fmaxf(fmaxf(v.x, v.y), fmaxf(v.z, v.w)));
        }
        mds[t] = m;
        return;
    }
    // ---- reduce path: contiguous 64 KB stream per block ----
    const int rb = bid - PBLOCKS;
    const float* p = F + (size_t)rb * RCHUNK + threadIdx.x * 4;
    f4 v[16];
#pragma unroll
    for (int k = 0; k < 16; ++k)
        v[k] = *(const f4*)(p + k * (RTHREADS * 4));   // sequential 4 KB steps
    double s0 = 0, s1 = 0, s2 = 0, s3 = 0;
    double q0 = 0, q1 = 0, q2 = 0, q3 = 0;
#pragma unroll
    for (int k = 0; k < 16; k += 4) {
        {
            f4 w = v[k + 0];
            s0 += (double)((w.x + w.y) + (w.z + w.w));
            q0 += (double)((w.x * w.x + w.y * w.y) + (w.z * w.z + w.w * w.w));
        }
        {
            f4 w = v[k + 1];
            s1 += (double)((w.x + w.y) + (w.z + w.w));
            q1 += (double)((w.x * w.x + w.y * w.y) + (w.z * w.z + w.w * w.w));
        }
        {
            f4 w = v[k + 2];
            s2 += (double)((w.x + w.y) + (w.z + w.w));
            q2 += (double)((w.x * w.x + w.y * w.y) + (w.z * w.z + w.w * w.w));
        }
        {
            f4 w = v[k + 3];
            s3 += (double)((w.x + w.y) + (w.z + w.w));
            q3 += (double)((w.x * w.x + w.y * w.y) + (w.z * w.z + w.w * w.w));
        }
    }
    double s = (s0 + s1) + (s2 + s3);
    double q = (q0 + q1) + (q2 + q3);
    for (int off = 32; off > 0; off >>= 1) {
        s += __shfl_down(s, off);
        q += __shfl_down(q, off);
    }
    int lane = threadIdx.x & 63, wv = threadIdx.x >> 6;
    if (lane == 0) { ls[wv] = s; lq[wv] = q; }
    __syncthreads();
    if (threadIdx.x == 0) {
        double S_ = 0.0, Q_ = 0.0;
        for (int w = 0; w < 4; ++w) { S_ += ls[w]; Q_ += lq[w]; }
        part[rb] = make_double2(S_, Q_);
    }
}

// On-the-fly D: the reference's 5-iteration masked box-dilation on a 0/1 mask
// equals a capped Chebyshev distance transform: D = 2^-d where d (<=5) is the
// Chebyshev distance to the nearest nonzero pooled-mask pixel; 0 if d > 5;
// the pooled value itself if nonzero. P(pixel==0) = 2^-16, so the search
// branch almost never executes. (Correctness verified in round 5.)
__device__ __forceinline__ float dt_val(const float* __restrict__ mds,
                                        int ib, int h, int w) {
    int best = 6;
    for (int dh = -5; dh <= 5; ++dh) {
        int hh = h + dh;
        if ((unsigned)hh >= (unsigned)HF) continue;
        for (int dw = -5; dw <= 5; ++dw) {
            int ww = w + dw;
            if ((unsigned)ww >= (unsigned)WF) continue;
            if (mds[(ib << 14) | (hh << 7) | ww] != 0.0f) {
                int ad = abs(dh) > abs(dw) ? abs(dh) : abs(dw);
                best = best < ad ? best : ad;
            }
        }
    }
    const float tbl[7] = {1.0f, 0.5f, 0.25f, 0.125f, 0.0625f, 0.03125f, 0.0f};
    return tbl[best];
}

// Fused epilogue: per-block redundant stats reduction (2048 double2 = 32 KB,
// L2/L3-broadcast) + on-the-fly D + channel-grouped normalization.
// ROUND-6 FIX vs round 5: out stores back to NONTEMPORAL (write-around).
// Round-5's plain allocating stores regressed ~6 us (134 MB of out lines
// polluting L3, evicting warm F + extra write-back). Everything else is the
// round-5 passed kernel unchanged.
constexpr int CGRP = 8;
__global__ void __launch_bounds__(256) k_final(const float* __restrict__ F,
                        const float* __restrict__ img_ds,
                        const float* __restrict__ mds,
                        const float* __restrict__ gw, const float* __restrict__ gb,
                        const float* __restrict__ bw, const float* __restrict__ bb,
                        const double2* __restrict__ part,
                        float* __restrict__ out) {
    // ---- stats preamble (identical result in every block) ----
    __shared__ double ls[4], lq[4];
    __shared__ float s_stats[2];
    {
        double s = 0.0, q = 0.0;
        for (int k = 0; k < 8; ++k) {
            double2 p = part[k * 256 + threadIdx.x];
            s += p.x; q += p.y;
        }
        for (int off = 32; off > 0; off >>= 1) {
            s += __shfl_down(s, off);
            q += __shfl_down(q, off);
        }
        int lane = threadIdx.x & 63, wv = threadIdx.x >> 6;
        if (lane == 0) { ls[wv] = s; lq[wv] = q; }
        __syncthreads();
        if (threadIdx.x == 0) {
            double S_ = (ls[0] + ls[1]) + (ls[2] + ls[3]);
            double Q_ = (lq[0] + lq[1]) + (lq[2] + lq[3]);
            double mean = S_ / (double)NTOT;
            double var  = (Q_ - (double)NTOT * mean * mean) / (double)(NTOT - 1);
            s_stats[0] = (float)mean;
            s_stats[1] = (float)(1.0 / sqrt(var * var + 1e-5));
        }
        __syncthreads();
    }
    const float meanf = s_stats[0];
    const float rstd  = s_stats[1];

    // grid = 1024 blocks x 256 threads.
    // blockIdx bits: [0:2) ihh4, [2:7) icg, [7:10) ib   (all block-uniform)
    // threadIdx bits: [0:5) iw, [5:8) ih_lo
    const int ihh4 = blockIdx.x & 3;
    const int icg  = (blockIdx.x >> 2) & 31;
    const int ib   = blockIdx.x >> 7;
    const int iw   = threadIdx.x & 31;
    const int w4   = iw * 4;
    const int c0   = icg * CGRP;

    const float* ip = img_ds + ((size_t)ib * 3 << 14);

    for (int sub = 0; sub < 4; ++sub) {
        const int ih = ihh4 * 32 + sub * 8 + (threadIdx.x >> 5);
        const int pixoff = (ih << 7) | w4;
        const int pix = (ib << 14) | pixoff;

        f4 m4 = *(const f4*)(mds + pix);
        f4 D;
        D.x = (m4.x != 0.0f) ? m4.x : dt_val(mds, ib, ih, w4 + 0);
        D.y = (m4.y != 0.0f) ? m4.y : dt_val(mds, ib, ih, w4 + 1);
        D.z = (m4.z != 0.0f) ? m4.z : dt_val(mds, ib, ih, w4 + 2);
        D.w = (m4.w != 0.0f) ? m4.w : dt_val(mds, ib, ih, w4 + 3);

        f4 R  = *(const f4*)(ip + ((0 << 14) | pixoff));
        f4 G  = *(const f4*)(ip + ((1 << 14) | pixoff));
        f4 Bl = *(const f4*)(ip + ((2 << 14) | pixoff));

        const size_t fbase = (((size_t)(ib * CF + c0)) << 14) + pixoff;

        f4 Fv[CGRP];
#pragma unroll
        for (int j = 0; j < CGRP; ++j)
            Fv[j] = *(const f4*)(F + fbase + ((size_t)j << 14));

#pragma unroll
        for (int j = 0; j < CGRP; ++j) {
            const int c = c0 + j;
            float g0 = gw[c * 3], g1 = gw[c * 3 + 1], g2 = gw[c * 3 + 2], gbi = gb[c];
            float b0 = bw[c * 3], b1 = bw[c * 3 + 1], b2 = bw[c * 3 + 2], bbi = bb[c];
            f4 o;
            {
                float gam = (R.x * g0 + G.x * g1 + Bl.x * g2 + gbi) * D.x;
                float bet = (R.x * b0 + G.x * b1 + Bl.x * b2 + bbi) * D.x;
                o.x = (Fv[j].x - meanf) * rstd * gam + bet;
            }
            {
                float gam = (R.y * g0 + G.y * g1 + Bl.y * g2 + gbi) * D.y;
                float bet = (R.y * b0 + G.y * b1 + Bl.y * b2 + bbi) * D.y;
                o.y = (Fv[j].y - meanf) * rstd * gam + bet;
            }
            {
                float gam = (R.z * g0 + G.z * g1 + Bl.z * g2 + gbi) * D.z;
                float bet = (R.z * b0 + G.z * b1 + Bl.z * b2 + bbi) * D.z;
                o.z = (Fv[j].z - meanf) * rstd * gam + bet;
            }
            {
                float gam = (R.w * g0 + G.w * g1 + Bl.w * g2 + gbi) * D.w;
                float bet = (R.w * b0 + G.w * b1 + Bl.w * b2 + bbi) * D.w;
                o.w = (Fv[j].w - meanf) * rstd * gam + bet;
            }
            __builtin_nontemporal_store(o, (f4*)(out + fbase + ((size_t)j << 14)));
        }
    }
}

extern "C" void kernel_launch(void* const* d_in, const int* in_sizes, int n_in,
                              void* d_out, int out_size, void* d_ws, size_t ws_size,
                              hipStream_t stream) {
    const float* F_in  = (const float*)d_in[0];
    const float* img_p = (const float*)d_in[1];
    const float* mask  = (const float*)d_in[2];
    const float* gw    = (const float*)d_in[3];
    const float* gb    = (const float*)d_in[4];
    const float* bw    = (const float*)d_in[5];
    const float* bb    = (const float*)d_in[6];
    float* out = (float*)d_out;

    float*   mds    = (float*)((char*)d_ws + DH_OFF);
    float*   img_ds = (float*)((char*)d_ws + IMG_OFF);
    double2* part   = (double2*)((char*)d_ws + PART_OFF);

    k_reduce_pool<<<PBLOCKS + RBLOCKS, RTHREADS, 0, stream>>>(
        F_in, img_p, mask, img_ds, mds, part);
    k_final<<<8 * 32 * 4, 256, 0, stream>>>(
        F_in, img_ds, mds, gw, gb, bw, bb, part, out);
}